// Round 13
// baseline (201.070 us; speedup 1.0000x reference)
//
#include <hip/hip_runtime.h>
#include <hip/hip_fp16.h>
#include <math.h>
#include <stdint.h>

static constexpr int kN     = 50000;
static constexpr int kFIn   = 128;
static constexpr int kHeads = 4;
static constexpr int kScanB = 256;
static constexpr int kScanNB = (kN + kScanB - 1) / kScanB;   // 196

__device__ __forceinline__ float lrelu(float x) { return x > 0.f ? x : 0.2f * x; }

// value-level (address-free) unpack/pack of 2 halves in a float's bits
__device__ __forceinline__ float2 h2pair(float fbits) {
    const uint32_t u = __float_as_uint(fbits);
    const __half2 h = __builtin_bit_cast(__half2, u);
    return __half22float2(h);
}
__device__ __forceinline__ float pack2h(float a, float b) {
    const __half2 h = __floats2half2_rn(a, b);
    return __uint_as_float(__builtin_bit_cast(uint32_t, h));
}

// ---- init: zero deg + cnt (contiguous) ----
__global__ void k_init(int* __restrict__ p, int n) {
    int i = blockIdx.x * blockDim.x + threadIdx.x;
    if (i < n) p[i] = 0;
}

// ---- layer 1 node transform: h1 = x@W1 (fp16 out), attention logits fused.
// W1 in LDS fp16 (32 KB, granule-rotated, conflict-free — R12 verified clean:
// VGPR 84, 0 conflicts). R13: x tile ALSO fp16 (8 KB) — R12 cycle model showed
// the kernel LDS-pipe-bound with x-reads = 256/288 of ds_read_b128 traffic;
// fp16-x halves that. LDS 40 KB -> 4 blocks/CU; grid 1024 (R12 miss: grid=512
// capped occupancy at 2 blocks/CU regardless of LDS). Unpack stays value-level;
// per-iter live set identical to R12 (8 x-floats replace the xa/xb float4 pair).
__global__ __launch_bounds__(256)
void k_gemm1(const float* __restrict__ x, const float* __restrict__ W1,
             const float* __restrict__ a_src1, const float* __restrict__ a_dst1,
             __half* __restrict__ h1h, float* __restrict__ asrc, float* __restrict__ adst,
             int nPass, int grid) {
    __shared__ __align__(16) float whf[128 * 16 * 4];  // 32 KB (fp16 W1, rotated granules)
    __shared__ __align__(16) float xsf[32 * 16 * 4];   //  8 KB (fp16 x tile, linear granules)
    const int t = threadIdx.x;
    const int j = t & 63;                            // lane
    const int g = t >> 6;                            // wave 0..3
    // stage W1 -> fp16 granules: idx -> (c = idx>>7 in 0..15, col = idx&127)
    for (int idx = t; idx < 2048; idx += 256) {
        const int c = idx >> 7, col = idx & 127;
        float4 st;
        st.x = pack2h(W1[(8 * c + 0) * 128 + col], W1[(8 * c + 1) * 128 + col]);
        st.y = pack2h(W1[(8 * c + 2) * 128 + col], W1[(8 * c + 3) * 128 + col]);
        st.z = pack2h(W1[(8 * c + 4) * 128 + col], W1[(8 * c + 5) * 128 + col]);
        st.w = pack2h(W1[(8 * c + 6) * 128 + col], W1[(8 * c + 7) * 128 + col]);
        const int gran = col * 16 + ((c + col) & 15);
        *reinterpret_cast<float4*>(&whf[gran * 4]) = st;
    }
    const float as0 = a_src1[j], as1 = a_src1[j + 64];
    const float ad0 = a_dst1[j], ad1 = a_dst1[j + 64];
    __syncthreads();

    for (int pass = blockIdx.x; pass < nPass; pass += grid) {
        const int nodeBase = pass * 32;
        // stage x -> fp16: 512 granules (node nn, k-chunk ck of 8), coalesced reads
        for (int q = t; q < 512; q += 256) {
            const int nn = q >> 4, ck = q & 15;
            int n = nodeBase + nn; if (n >= kN) n = kN - 1;
            const float4 xa = *reinterpret_cast<const float4*>(&x[(size_t)n * 128 + ck * 8]);
            const float4 xb = *reinterpret_cast<const float4*>(&x[(size_t)n * 128 + ck * 8 + 4]);
            float4 st;
            st.x = pack2h(xa.x, xa.y);
            st.y = pack2h(xa.z, xa.w);
            st.z = pack2h(xb.x, xb.y);
            st.w = pack2h(xb.z, xb.w);
            *reinterpret_cast<float4*>(&xsf[q * 4]) = st;
        }
        __syncthreads();

        const int base = g * 8;
        float acc[2][8] = {};
#pragma unroll 4
        for (int c = 0; c < 16; ++c) {               // 8 k-values per iter
            const int rot = (c + j) & 15;            // ch j+64: same rot (64&15==0)
            const float4 w0raw = *(const float4*)&whf[(j * 16 + rot) * 4];
            const float4 w1raw = *(const float4*)&whf[((j + 64) * 16 + rot) * 4];
            const float2 a01 = h2pair(w0raw.x), a23 = h2pair(w0raw.y);
            const float2 a45 = h2pair(w0raw.z), a67 = h2pair(w0raw.w);
            const float2 b01 = h2pair(w1raw.x), b23 = h2pair(w1raw.y);
            const float2 b45 = h2pair(w1raw.z), b67 = h2pair(w1raw.w);
#pragma unroll
            for (int nn = 0; nn < 8; ++nn) {
                const float4 xr = *(const float4*)&xsf[((base + nn) * 16 + c) * 4]; // broadcast
                const float2 x01 = h2pair(xr.x), x23 = h2pair(xr.y);
                const float2 x45 = h2pair(xr.z), x67 = h2pair(xr.w);
                acc[0][nn] += a01.x * x01.x + a01.y * x01.y + a23.x * x23.x + a23.y * x23.y
                            + a45.x * x45.x + a45.y * x45.y + a67.x * x67.x + a67.y * x67.y;
                acc[1][nn] += b01.x * x01.x + b01.y * x01.y + b23.x * x23.x + b23.y * x23.y
                            + b45.x * x45.x + b45.y * x45.y + b67.x * x67.x + b67.y * x67.y;
            }
        }
#pragma unroll
        for (int nn = 0; nn < 8; ++nn) {
            const int n = nodeBase + base + nn;
            const bool valid = (n < kN);
            if (valid) {
                h1h[(size_t)n * 128 + j]      = __float2half(acc[0][nn]);
                h1h[(size_t)n * 128 + 64 + j] = __float2half(acc[1][nn]);
            }
            float ps0 = acc[0][nn] * as0, ps1 = acc[1][nn] * as1;
            float pd0 = acc[0][nn] * ad0, pd1 = acc[1][nn] * ad1;
#pragma unroll
            for (int off = 16; off >= 1; off >>= 1) {
                ps0 += __shfl_xor(ps0, off, 64);
                ps1 += __shfl_xor(ps1, off, 64);
                pd0 += __shfl_xor(pd0, off, 64);
                pd1 += __shfl_xor(pd1, off, 64);
            }
            if (valid && ((j & 31) == 0)) {
                const int h01 = j >> 5;
                asrc[n * 4 + h01]     = ps0;
                asrc[n * 4 + 2 + h01] = ps1;
                adst[n * 4 + h01]     = pd0;
                adst[n * 4 + 2 + h01] = pd1;
            }
        }
        __syncthreads();
    }
}

// ---- CSR build ----
__global__ void k_hist(const int* __restrict__ ei, int E, int* __restrict__ deg) {
    int i = blockIdx.x * blockDim.x + threadIdx.x;
    int total = E + kN;
    if (i >= total) return;
    int d = (i < E) ? ei[E + i] : (i - E);
    atomicAdd(&deg[d], 1);
}

__global__ void k_scan_a(const int* __restrict__ deg, int* __restrict__ loc, int* __restrict__ bsum) {
    __shared__ int tmp[kScanB];
    int t = threadIdx.x;
    int i = blockIdx.x * kScanB + t;
    int v = (i < kN) ? deg[i] : 0;
    tmp[t] = v;
    __syncthreads();
    for (int off = 1; off < kScanB; off <<= 1) {
        int add = (t >= off) ? tmp[t - off] : 0;
        __syncthreads();
        tmp[t] += add;
        __syncthreads();
    }
    if (i < kN) loc[i] = tmp[t] - v;     // exclusive within block
    if (t == kScanB - 1) bsum[blockIdx.x] = tmp[t];
}

__global__ void k_scan_b(int* __restrict__ bsum) {
    __shared__ int tmp[256];
    int t = threadIdx.x;
    int v = (t < kScanNB) ? bsum[t] : 0;
    tmp[t] = v;
    __syncthreads();
    for (int off = 1; off < 256; off <<= 1) {
        int add = (t >= off) ? tmp[t - off] : 0;
        __syncthreads();
        tmp[t] += add;
        __syncthreads();
    }
    if (t < kScanNB) bsum[t] = tmp[t] - v;   // exclusive
}

__global__ void k_scan_c(const int* __restrict__ loc, const int* __restrict__ bsum,
                         int* __restrict__ rowptr, int E2) {
    int i = blockIdx.x * kScanB + threadIdx.x;
    if (i < kN) rowptr[i] = loc[i] + bsum[blockIdx.x];
    if (i == 0) rowptr[kN] = E2;
}

// ---- scatter: bucket edges by dst AND precompute the 4 per-edge softmax weights ----
__global__ void k_scatter(const int* __restrict__ ei, int E,
                          const float* __restrict__ asrc, const float* __restrict__ adst,
                          const int* __restrict__ rowptr, int* __restrict__ cnt,
                          int* __restrict__ es, float* __restrict__ wgt) {
    int i = blockIdx.x * blockDim.x + threadIdx.x;
    int total = E + kN;
    if (i >= total) return;
    int s, d;
    if (i < E) { s = ei[i]; d = ei[E + i]; } else { s = d = i - E; }
    int pos = rowptr[d] + atomicAdd(&cnt[d], 1);
    es[pos] = s;
    float4 w4;
    w4.x = expf(lrelu(asrc[s * 4 + 0] + adst[d * 4 + 0]));
    w4.y = expf(lrelu(asrc[s * 4 + 1] + adst[d * 4 + 1]));
    w4.z = expf(lrelu(asrc[s * 4 + 2] + adst[d * 4 + 2]));
    w4.w = expf(lrelu(asrc[s * 4 + 3] + adst[d * 4 + 3]));
    *reinterpret_cast<float4*>(&wgt[pos * 4]) = w4;
}

// ---- layer 1 aggregation: pure gather+FMA (weights preloaded), 4-unrolled ----
__global__ __launch_bounds__(256)
void k_agg1(const int* __restrict__ rowptr, const int* __restrict__ es,
            const float* __restrict__ wgt,
            const __half* __restrict__ h1h, const float* __restrict__ b1,
            const float* __restrict__ W2, float* __restrict__ h2) {
    const int n = blockIdx.x * 4 + (threadIdx.x >> 6);
    if (n >= kN) return;
    const int j  = threadIdx.x & 63;     // lane: channels 2j, 2j+1
    const int hh = j >> 4;               // head of both channels
    const int beg = rowptr[n], end = rowptr[n + 1];
    float ax0 = 0.f, ay0 = 0.f, dn0 = 0.f;
    float ax1 = 0.f, ay1 = 0.f, dn1 = 0.f;
    int p = beg;
    for (; p + 4 <= end; p += 4) {
        const int s0 = es[p],     s1 = es[p + 1];
        const int s2 = es[p + 2], s3 = es[p + 3];
        const float w0 = wgt[(p + 0) * 4 + hh];
        const float w1 = wgt[(p + 1) * 4 + hh];
        const float w2 = wgt[(p + 2) * 4 + hh];
        const float w3 = wgt[(p + 3) * 4 + hh];
        const float2 f0 = __half22float2(*(const __half2*)&h1h[s0 * 128 + 2 * j]);
        const float2 f1 = __half22float2(*(const __half2*)&h1h[s1 * 128 + 2 * j]);
        const float2 f2 = __half22float2(*(const __half2*)&h1h[s2 * 128 + 2 * j]);
        const float2 f3 = __half22float2(*(const __half2*)&h1h[s3 * 128 + 2 * j]);
        ax0 += w0 * f0.x; ay0 += w0 * f0.y; dn0 += w0;
        ax1 += w1 * f1.x; ay1 += w1 * f1.y; dn1 += w1;
        ax0 += w2 * f2.x; ay0 += w2 * f2.y; dn0 += w2;
        ax1 += w3 * f3.x; ay1 += w3 * f3.y; dn1 += w3;
    }
    for (; p < end; ++p) {
        const int s0 = es[p];
        const float w0 = wgt[p * 4 + hh];
        const float2 f0 = __half22float2(*(const __half2*)&h1h[s0 * 128 + 2 * j]);
        ax0 += w0 * f0.x; ay0 += w0 * f0.y; dn0 += w0;
    }
    const float den = dn0 + dn1;
    float vx = (ax0 + ax1) / den;
    float vy = (ay0 + ay1) / den;
    vx += __shfl_xor(vx, 32, 64); vy += __shfl_xor(vy, 32, 64);
    vx += __shfl_xor(vx, 16, 64); vy += __shfl_xor(vy, 16, 64);
    const int m = j & 15;
    float u0 = 0.25f * vx + b1[2 * m];
    float u1 = 0.25f * vy + b1[2 * m + 1];
    u0 = u0 > 0.f ? u0 : expf(u0) - 1.f;
    u1 = u1 > 0.f ? u1 : expf(u1) - 1.f;
    float tsum = u0 * W2[2 * m] + u1 * W2[2 * m + 1];
    tsum += __shfl_xor(tsum, 8, 64);
    tsum += __shfl_xor(tsum, 4, 64);
    tsum += __shfl_xor(tsum, 2, 64);
    tsum += __shfl_xor(tsum, 1, 64);
    if (j == 0) h2[n] = tsum;
}

// ---- layer 2: 16 lanes per node, gather h2 (L2-resident), fused bias -> out ----
__global__ __launch_bounds__(256)
void k_agg2(const int* __restrict__ rowptr, const int* __restrict__ es,
            const float* __restrict__ h2,
            const float* __restrict__ a_s2, const float* __restrict__ a_d2,
            const float* __restrict__ b2, float* __restrict__ out) {
    const int n = blockIdx.x * 16 + (threadIdx.x >> 4);
    if (n >= kN) return;
    const int l = threadIdx.x & 15;
    const float as = a_s2[0], ad = a_d2[0];
    const int beg = rowptr[n], end = rowptr[n + 1];
    const float hd = h2[n] * ad;
    float sw = 0.f, swh = 0.f;
    for (int p = beg + l; p < end; p += 16) {
        float hs = h2[es[p]];
        float w = expf(lrelu(hs * as + hd));
        sw += w;
        swh += w * hs;
    }
#pragma unroll
    for (int off = 8; off >= 1; off >>= 1) {
        sw  += __shfl_xor(sw, off, 64);
        swh += __shfl_xor(swh, off, 64);
    }
    if (l == 0) out[n] = swh / sw + b2[0];
}

extern "C" void kernel_launch(void* const* d_in, const int* in_sizes, int n_in,
                              void* d_out, int out_size, void* d_ws, size_t ws_size,
                              hipStream_t stream) {
    const float* x      = (const float*)d_in[0];
    const int*   ei     = (const int*)d_in[1];
    const float* W1     = (const float*)d_in[3];
    const float* a_src1 = (const float*)d_in[4];
    const float* a_dst1 = (const float*)d_in[5];
    const float* b1     = (const float*)d_in[6];
    const float* W2     = (const float*)d_in[7];
    const float* a_src2 = (const float*)d_in[8];
    const float* a_dst2 = (const float*)d_in[9];
    const float* b2     = (const float*)d_in[10];
    float* out = (float*)d_out;

    const int E  = in_sizes[1] / 2;      // 800000
    const int E2 = E + kN;               // 850000

    // workspace layout (float offsets)
    float*  ws    = (float*)d_ws;
    float*  asrc  = ws;                          //   200,000 f
    float*  adst  = ws + 200000;                 //   200,000 f
    float*  h2    = ws + 400000;                 //    50,000 f
    __half* h1h   = (__half*)(ws + 450000);      // 6,400,000 h = 3,200,000 f
    float*  wgt   = ws + 3650000;                // 3,400,000 f (per-edge weights x4)
    int*    ibase = (int*)(ws + 7050000);
    int*    es     = ibase;                      //   850,000 i
    int*    deg    = ibase + 850000;             //    50,000 i
    int*    cnt    = ibase + 900000;             //    50,000 i
    int*    loc    = ibase + 950000;             //    50,000 i
    int*    rowptr = ibase + 1000000;            //    50,001 i
    int*    bsum   = ibase + 1050016;            //       256 i

    k_init<<<(100000 + 255) / 256, 256, 0, stream>>>(deg, 100000);  // deg+cnt contiguous

    k_hist<<<(E2 + 255) / 256, 256, 0, stream>>>(ei, E, deg);
    k_scan_a<<<kScanNB, kScanB, 0, stream>>>(deg, loc, bsum);
    k_scan_b<<<1, 256, 0, stream>>>(bsum);
    k_scan_c<<<kScanNB, kScanB, 0, stream>>>(loc, bsum, rowptr, E2);

    {
        const int nPass = (kN + 31) / 32;        // 1563
        k_gemm1<<<1024, 256, 0, stream>>>(x, W1, a_src1, a_dst1, h1h, asrc, adst, nPass, 1024);
    }

    k_scatter<<<(E2 + 255) / 256, 256, 0, stream>>>(ei, E, asrc, adst, rowptr, cnt, es, wgt);

    k_agg1<<<(kN + 3) / 4, 256, 0, stream>>>(rowptr, es, wgt, h1h, b1, W2, h2);

    k_agg2<<<(kN + 15) / 16, 256, 0, stream>>>(rowptr, es, h2, a_src2, a_dst2, b2, out);
}

// Round 14
// 168.248 us; speedup vs baseline: 1.1951x; 1.1951x over previous
//
#include <hip/hip_runtime.h>
#include <hip/hip_fp16.h>
#include <math.h>
#include <stdint.h>

static constexpr int kN     = 50000;
static constexpr int kFIn   = 128;
static constexpr int kHeads = 4;
static constexpr int kScanB = 256;
static constexpr int kScanNB = (kN + kScanB - 1) / kScanB;   // 196

typedef _Float16 half8v  __attribute__((ext_vector_type(8)));
typedef float    floatx4 __attribute__((ext_vector_type(4)));

__device__ __forceinline__ float lrelu(float x) { return x > 0.f ? x : 0.2f * x; }

// value-level (address-free) pack of 2 floats -> 2 halves in a float's bits
__device__ __forceinline__ float pack2h(float a, float b) {
    const __half2 h = __floats2half2_rn(a, b);
    return __uint_as_float(__builtin_bit_cast(uint32_t, h));
}

// ---- init: zero deg + cnt (contiguous) ----
__global__ void k_init(int* __restrict__ p, int n) {
    int i = blockIdx.x * blockDim.x + threadIdx.x;
    if (i < n) p[i] = 0;
}

// ---- layer 1 node transform via MFMA: h1 = fp16(x) @ fp16(W1), f32 accum.
// R13 post-mortem: the scalar-FMA version hit its structural VALU ceiling (~62us,
// VALUBusy 53%, occupancy pinned ~17% regardless of LDS). MFMA moves the 1.64
// GFLOP to the matrix pipe: 64 MFMA per 32-node pass (~320cyc) -> HBM-bound on x.
// LDS layouts: W1 fp16 granule-rotated (ch j, k-chunk c at granule j*16+((c+j)&15))
// == B-fragment layout (lane=col l&15, k-chunk 8*(l>>4)+j); x tile same rotation
// by node == A-fragment layout. Both verified conflict-free (0 conflicts R8-R13).
// D layout (HW-verified m89): col=lane&15, row=(lane>>4)*4+reg.
// Per wave: row-tile (g&1), col-tiles 4*(g>>1)..+3, 4 K-steps -> 16 MFMA, 4xf32x4 acc.
__global__ __launch_bounds__(256)
void k_gemm1(const float* __restrict__ x, const float* __restrict__ W1,
             __half* __restrict__ h1h, int nPass, int grid) {
    __shared__ __align__(16) float whf[128 * 16 * 4];  // 32 KB (fp16 W1, rotated granules)
    __shared__ __align__(16) float xsf[32 * 16 * 4];   //  8 KB (fp16 x tile, rotated granules)
    const int t = threadIdx.x;
    const int l = t & 63;
    const int g = t >> 6;                            // wave 0..3
    // stage W1 -> fp16 granules (same staging as R12/R13, verified clean)
    for (int idx = t; idx < 2048; idx += 256) {
        const int c = idx >> 7, col = idx & 127;
        float4 st;
        st.x = pack2h(W1[(8 * c + 0) * 128 + col], W1[(8 * c + 1) * 128 + col]);
        st.y = pack2h(W1[(8 * c + 2) * 128 + col], W1[(8 * c + 3) * 128 + col]);
        st.z = pack2h(W1[(8 * c + 4) * 128 + col], W1[(8 * c + 5) * 128 + col]);
        st.w = pack2h(W1[(8 * c + 6) * 128 + col], W1[(8 * c + 7) * 128 + col]);
        const int gran = col * 16 + ((c + col) & 15);
        *reinterpret_cast<float4*>(&whf[gran * 4]) = st;
    }
    __syncthreads();

    const int rt  = g & 1;                           // row-tile (16 nodes)
    const int ctB = (g >> 1) * 4;                    // first of 4 col-tiles
    const int lm  = l & 15;
    const int lk  = l >> 4;

    for (int pass = blockIdx.x; pass < nPass; pass += grid) {
        const int nodeBase = pass * 32;
        // stage x -> fp16 rotated granules: node nn, k-chunk ck (8 halves = 16B)
        for (int q = t; q < 512; q += 256) {
            const int nn = q >> 4, ck = q & 15;
            int n = nodeBase + nn; if (n >= kN) n = kN - 1;
            const float4 xa = *reinterpret_cast<const float4*>(&x[(size_t)n * 128 + ck * 8]);
            const float4 xb = *reinterpret_cast<const float4*>(&x[(size_t)n * 128 + ck * 8 + 4]);
            float4 st;
            st.x = pack2h(xa.x, xa.y);
            st.y = pack2h(xa.z, xa.w);
            st.z = pack2h(xb.x, xb.y);
            st.w = pack2h(xb.z, xb.w);
            const int gran = nn * 16 + ((ck + nn) & 15);
            *reinterpret_cast<float4*>(&xsf[gran * 4]) = st;
        }
        __syncthreads();

        floatx4 acc0 = {0.f, 0.f, 0.f, 0.f};
        floatx4 acc1 = {0.f, 0.f, 0.f, 0.f};
        floatx4 acc2 = {0.f, 0.f, 0.f, 0.f};
        floatx4 acc3 = {0.f, 0.f, 0.f, 0.f};
        const int node = rt * 16 + lm;               // A row for this lane
        const int ch0  = ctB * 16 + lm;              // B col for this lane (tile 0)
#pragma unroll
        for (int kk = 0; kk < 4; ++kk) {
            const int ck = lk + 4 * kk;              // this lane's k-chunk (8 halves)
            const half8v af = *reinterpret_cast<const half8v*>(
                &xsf[(node * 16 + ((ck + node) & 15)) * 4]);
            const half8v b0 = *reinterpret_cast<const half8v*>(
                &whf[((ch0 +  0) * 16 + ((ck + ch0 +  0) & 15)) * 4]);
            const half8v b1 = *reinterpret_cast<const half8v*>(
                &whf[((ch0 + 16) * 16 + ((ck + ch0 + 16) & 15)) * 4]);
            const half8v b2 = *reinterpret_cast<const half8v*>(
                &whf[((ch0 + 32) * 16 + ((ck + ch0 + 32) & 15)) * 4]);
            const half8v b3 = *reinterpret_cast<const half8v*>(
                &whf[((ch0 + 48) * 16 + ((ck + ch0 + 48) & 15)) * 4]);
            acc0 = __builtin_amdgcn_mfma_f32_16x16x32_f16(af, b0, acc0, 0, 0, 0);
            acc1 = __builtin_amdgcn_mfma_f32_16x16x32_f16(af, b1, acc1, 0, 0, 0);
            acc2 = __builtin_amdgcn_mfma_f32_16x16x32_f16(af, b2, acc2, 0, 0, 0);
            acc3 = __builtin_amdgcn_mfma_f32_16x16x32_f16(af, b3, acc3, 0, 0, 0);
        }
        // D: col = lm, row = lk*4 + r
        const int nrow0 = nodeBase + rt * 16 + lk * 4;
#pragma unroll
        for (int r = 0; r < 4; ++r) {
            const int n = nrow0 + r;
            if (n < kN) {
                h1h[(size_t)n * 128 + ch0     ] = __float2half(acc0[r]);
                h1h[(size_t)n * 128 + ch0 + 16] = __float2half(acc1[r]);
                h1h[(size_t)n * 128 + ch0 + 32] = __float2half(acc2[r]);
                h1h[(size_t)n * 128 + ch0 + 48] = __float2half(acc3[r]);
            }
        }
        __syncthreads();
    }
}

// ---- attention logits from h1 (fp16): one wave per node, lane = 2 channels.
// head of lane j's channels (2j,2j+1) = j>>4; reduce within 16-lane head groups.
__global__ __launch_bounds__(256)
void k_logits(const __half* __restrict__ h1h,
              const float* __restrict__ a_src1, const float* __restrict__ a_dst1,
              float* __restrict__ asrc, float* __restrict__ adst) {
    const int n = blockIdx.x * 4 + (threadIdx.x >> 6);
    if (n >= kN) return;
    const int j = threadIdx.x & 63;
    const float2 f = __half22float2(*(const __half2*)&h1h[(size_t)n * 128 + 2 * j]);
    float ps = f.x * a_src1[2 * j] + f.y * a_src1[2 * j + 1];
    float pd = f.x * a_dst1[2 * j] + f.y * a_dst1[2 * j + 1];
#pragma unroll
    for (int off = 8; off >= 1; off >>= 1) {
        ps += __shfl_xor(ps, off, 64);
        pd += __shfl_xor(pd, off, 64);
    }
    if ((j & 15) == 0) {
        asrc[n * 4 + (j >> 4)] = ps;
        adst[n * 4 + (j >> 4)] = pd;
    }
}

// ---- CSR build ----
__global__ void k_hist(const int* __restrict__ ei, int E, int* __restrict__ deg) {
    int i = blockIdx.x * blockDim.x + threadIdx.x;
    int total = E + kN;
    if (i >= total) return;
    int d = (i < E) ? ei[E + i] : (i - E);
    atomicAdd(&deg[d], 1);
}

__global__ void k_scan_a(const int* __restrict__ deg, int* __restrict__ loc, int* __restrict__ bsum) {
    __shared__ int tmp[kScanB];
    int t = threadIdx.x;
    int i = blockIdx.x * kScanB + t;
    int v = (i < kN) ? deg[i] : 0;
    tmp[t] = v;
    __syncthreads();
    for (int off = 1; off < kScanB; off <<= 1) {
        int add = (t >= off) ? tmp[t - off] : 0;
        __syncthreads();
        tmp[t] += add;
        __syncthreads();
    }
    if (i < kN) loc[i] = tmp[t] - v;     // exclusive within block
    if (t == kScanB - 1) bsum[blockIdx.x] = tmp[t];
}

__global__ void k_scan_b(int* __restrict__ bsum) {
    __shared__ int tmp[256];
    int t = threadIdx.x;
    int v = (t < kScanNB) ? bsum[t] : 0;
    tmp[t] = v;
    __syncthreads();
    for (int off = 1; off < 256; off <<= 1) {
        int add = (t >= off) ? tmp[t - off] : 0;
        __syncthreads();
        tmp[t] += add;
        __syncthreads();
    }
    if (t < kScanNB) bsum[t] = tmp[t] - v;   // exclusive
}

__global__ void k_scan_c(const int* __restrict__ loc, const int* __restrict__ bsum,
                         int* __restrict__ rowptr, int E2) {
    int i = blockIdx.x * kScanB + threadIdx.x;
    if (i < kN) rowptr[i] = loc[i] + bsum[blockIdx.x];
    if (i == 0) rowptr[kN] = E2;
}

// ---- scatter: bucket edges by dst AND precompute the 4 per-edge softmax weights ----
__global__ void k_scatter(const int* __restrict__ ei, int E,
                          const float* __restrict__ asrc, const float* __restrict__ adst,
                          const int* __restrict__ rowptr, int* __restrict__ cnt,
                          int* __restrict__ es, float* __restrict__ wgt) {
    int i = blockIdx.x * blockDim.x + threadIdx.x;
    int total = E + kN;
    if (i >= total) return;
    int s, d;
    if (i < E) { s = ei[i]; d = ei[E + i]; } else { s = d = i - E; }
    int pos = rowptr[d] + atomicAdd(&cnt[d], 1);
    es[pos] = s;
    float4 w4;
    w4.x = expf(lrelu(asrc[s * 4 + 0] + adst[d * 4 + 0]));
    w4.y = expf(lrelu(asrc[s * 4 + 1] + adst[d * 4 + 1]));
    w4.z = expf(lrelu(asrc[s * 4 + 2] + adst[d * 4 + 2]));
    w4.w = expf(lrelu(asrc[s * 4 + 3] + adst[d * 4 + 3]));
    *reinterpret_cast<float4*>(&wgt[pos * 4]) = w4;
}

// ---- layer 1 aggregation: pure gather+FMA (weights preloaded), 4-unrolled ----
__global__ __launch_bounds__(256)
void k_agg1(const int* __restrict__ rowptr, const int* __restrict__ es,
            const float* __restrict__ wgt,
            const __half* __restrict__ h1h, const float* __restrict__ b1,
            const float* __restrict__ W2, float* __restrict__ h2) {
    const int n = blockIdx.x * 4 + (threadIdx.x >> 6);
    if (n >= kN) return;
    const int j  = threadIdx.x & 63;     // lane: channels 2j, 2j+1
    const int hh = j >> 4;               // head of both channels
    const int beg = rowptr[n], end = rowptr[n + 1];
    float ax0 = 0.f, ay0 = 0.f, dn0 = 0.f;
    float ax1 = 0.f, ay1 = 0.f, dn1 = 0.f;
    int p = beg;
    for (; p + 4 <= end; p += 4) {
        const int s0 = es[p],     s1 = es[p + 1];
        const int s2 = es[p + 2], s3 = es[p + 3];
        const float w0 = wgt[(p + 0) * 4 + hh];
        const float w1 = wgt[(p + 1) * 4 + hh];
        const float w2 = wgt[(p + 2) * 4 + hh];
        const float w3 = wgt[(p + 3) * 4 + hh];
        const float2 f0 = __half22float2(*(const __half2*)&h1h[s0 * 128 + 2 * j]);
        const float2 f1 = __half22float2(*(const __half2*)&h1h[s1 * 128 + 2 * j]);
        const float2 f2 = __half22float2(*(const __half2*)&h1h[s2 * 128 + 2 * j]);
        const float2 f3 = __half22float2(*(const __half2*)&h1h[s3 * 128 + 2 * j]);
        ax0 += w0 * f0.x; ay0 += w0 * f0.y; dn0 += w0;
        ax1 += w1 * f1.x; ay1 += w1 * f1.y; dn1 += w1;
        ax0 += w2 * f2.x; ay0 += w2 * f2.y; dn0 += w2;
        ax1 += w3 * f3.x; ay1 += w3 * f3.y; dn1 += w3;
    }
    for (; p < end; ++p) {
        const int s0 = es[p];
        const float w0 = wgt[p * 4 + hh];
        const float2 f0 = __half22float2(*(const __half2*)&h1h[s0 * 128 + 2 * j]);
        ax0 += w0 * f0.x; ay0 += w0 * f0.y; dn0 += w0;
    }
    const float den = dn0 + dn1;
    float vx = (ax0 + ax1) / den;
    float vy = (ay0 + ay1) / den;
    vx += __shfl_xor(vx, 32, 64); vy += __shfl_xor(vy, 32, 64);
    vx += __shfl_xor(vx, 16, 64); vy += __shfl_xor(vy, 16, 64);
    const int m = j & 15;
    float u0 = 0.25f * vx + b1[2 * m];
    float u1 = 0.25f * vy + b1[2 * m + 1];
    u0 = u0 > 0.f ? u0 : expf(u0) - 1.f;
    u1 = u1 > 0.f ? u1 : expf(u1) - 1.f;
    float tsum = u0 * W2[2 * m] + u1 * W2[2 * m + 1];
    tsum += __shfl_xor(tsum, 8, 64);
    tsum += __shfl_xor(tsum, 4, 64);
    tsum += __shfl_xor(tsum, 2, 64);
    tsum += __shfl_xor(tsum, 1, 64);
    if (j == 0) h2[n] = tsum;
}

// ---- layer 2: 16 lanes per node, gather h2 (L2-resident), fused bias -> out ----
__global__ __launch_bounds__(256)
void k_agg2(const int* __restrict__ rowptr, const int* __restrict__ es,
            const float* __restrict__ h2,
            const float* __restrict__ a_s2, const float* __restrict__ a_d2,
            const float* __restrict__ b2, float* __restrict__ out) {
    const int n = blockIdx.x * 16 + (threadIdx.x >> 4);
    if (n >= kN) return;
    const int l = threadIdx.x & 15;
    const float as = a_s2[0], ad = a_d2[0];
    const int beg = rowptr[n], end = rowptr[n + 1];
    const float hd = h2[n] * ad;
    float sw = 0.f, swh = 0.f;
    for (int p = beg + l; p < end; p += 16) {
        float hs = h2[es[p]];
        float w = expf(lrelu(hs * as + hd));
        sw += w;
        swh += w * hs;
    }
#pragma unroll
    for (int off = 8; off >= 1; off >>= 1) {
        sw  += __shfl_xor(sw, off, 64);
        swh += __shfl_xor(swh, off, 64);
    }
    if (l == 0) out[n] = swh / sw + b2[0];
}

extern "C" void kernel_launch(void* const* d_in, const int* in_sizes, int n_in,
                              void* d_out, int out_size, void* d_ws, size_t ws_size,
                              hipStream_t stream) {
    const float* x      = (const float*)d_in[0];
    const int*   ei     = (const int*)d_in[1];
    const float* W1     = (const float*)d_in[3];
    const float* a_src1 = (const float*)d_in[4];
    const float* a_dst1 = (const float*)d_in[5];
    const float* b1     = (const float*)d_in[6];
    const float* W2     = (const float*)d_in[7];
    const float* a_src2 = (const float*)d_in[8];
    const float* a_dst2 = (const float*)d_in[9];
    const float* b2     = (const float*)d_in[10];
    float* out = (float*)d_out;

    const int E  = in_sizes[1] / 2;      // 800000
    const int E2 = E + kN;               // 850000

    // workspace layout (float offsets)
    float*  ws    = (float*)d_ws;
    float*  asrc  = ws;                          //   200,000 f
    float*  adst  = ws + 200000;                 //   200,000 f
    float*  h2    = ws + 400000;                 //    50,000 f
    __half* h1h   = (__half*)(ws + 450000);      // 6,400,000 h = 3,200,000 f
    float*  wgt   = ws + 3650000;                // 3,400,000 f (per-edge weights x4)
    int*    ibase = (int*)(ws + 7050000);
    int*    es     = ibase;                      //   850,000 i
    int*    deg    = ibase + 850000;             //    50,000 i
    int*    cnt    = ibase + 900000;             //    50,000 i
    int*    loc    = ibase + 950000;             //    50,000 i
    int*    rowptr = ibase + 1000000;            //    50,001 i
    int*    bsum   = ibase + 1050016;            //       256 i

    k_init<<<(100000 + 255) / 256, 256, 0, stream>>>(deg, 100000);  // deg+cnt contiguous

    k_hist<<<(E2 + 255) / 256, 256, 0, stream>>>(ei, E, deg);
    k_scan_a<<<kScanNB, kScanB, 0, stream>>>(deg, loc, bsum);
    k_scan_b<<<1, 256, 0, stream>>>(bsum);
    k_scan_c<<<kScanNB, kScanB, 0, stream>>>(loc, bsum, rowptr, E2);

    {
        const int nPass = (kN + 31) / 32;        // 1563
        const int grid  = 782;                   // ~2 passes/block
        k_gemm1<<<grid, 256, 0, stream>>>(x, W1, h1h, nPass, grid);
    }

    k_logits<<<(kN + 3) / 4, 256, 0, stream>>>(h1h, a_src1, a_dst1, asrc, adst);

    k_scatter<<<(E2 + 255) / 256, 256, 0, stream>>>(ei, E, asrc, adst, rowptr, cnt, es, wgt);

    k_agg1<<<(kN + 3) / 4, 256, 0, stream>>>(rowptr, es, wgt, h1h, b1, W2, h2);

    k_agg2<<<(kN + 15) / 16, 256, 0, stream>>>(rowptr, es, h2, a_src2, a_dst2, b2, out);
}

// Round 15
// 145.590 us; speedup vs baseline: 1.3811x; 1.1556x over previous
//
#include <hip/hip_runtime.h>
#include <hip/hip_fp16.h>
#include <math.h>
#include <stdint.h>

static constexpr int kN     = 50000;
static constexpr int kFIn   = 128;
static constexpr int kHeads = 4;
static constexpr int kScanB = 256;
static constexpr int kScanNB = (kN + kScanB - 1) / kScanB;   // 196

typedef _Float16 half8v  __attribute__((ext_vector_type(8)));
typedef float    floatx4 __attribute__((ext_vector_type(4)));

__device__ __forceinline__ float lrelu(float x) { return x > 0.f ? x : 0.2f * x; }

// value-level (address-free) pack of 2 floats -> 2 halves in a float's bits
__device__ __forceinline__ float pack2h(float a, float b) {
    const __half2 h = __floats2half2_rn(a, b);
    return __uint_as_float(__builtin_bit_cast(uint32_t, h));
}

// ---- init: zero deg ----
__global__ void k_init(int* __restrict__ p, int n) {
    int i = blockIdx.x * blockDim.x + threadIdx.x;
    if (i < n) p[i] = 0;
}

// ---- layer 1 node transform via MFMA: h1 = fp16(x) @ fp16(W1), f32 accum.
// (R14 verified: gemm1 off the top-5; fragment layouts correct, absmax unchanged.)
__global__ __launch_bounds__(256)
void k_gemm1(const float* __restrict__ x, const float* __restrict__ W1,
             __half* __restrict__ h1h, int nPass, int grid) {
    __shared__ __align__(16) float whf[128 * 16 * 4];  // 32 KB (fp16 W1, rotated granules)
    __shared__ __align__(16) float xsf[32 * 16 * 4];   //  8 KB (fp16 x tile, rotated granules)
    const int t = threadIdx.x;
    const int l = t & 63;
    const int g = t >> 6;                            // wave 0..3
    for (int idx = t; idx < 2048; idx += 256) {
        const int c = idx >> 7, col = idx & 127;
        float4 st;
        st.x = pack2h(W1[(8 * c + 0) * 128 + col], W1[(8 * c + 1) * 128 + col]);
        st.y = pack2h(W1[(8 * c + 2) * 128 + col], W1[(8 * c + 3) * 128 + col]);
        st.z = pack2h(W1[(8 * c + 4) * 128 + col], W1[(8 * c + 5) * 128 + col]);
        st.w = pack2h(W1[(8 * c + 6) * 128 + col], W1[(8 * c + 7) * 128 + col]);
        const int gran = col * 16 + ((c + col) & 15);
        *reinterpret_cast<float4*>(&whf[gran * 4]) = st;
    }
    __syncthreads();

    const int rt  = g & 1;                           // row-tile (16 nodes)
    const int ctB = (g >> 1) * 4;                    // first of 4 col-tiles
    const int lm  = l & 15;
    const int lk  = l >> 4;

    for (int pass = blockIdx.x; pass < nPass; pass += grid) {
        const int nodeBase = pass * 32;
        for (int q = t; q < 512; q += 256) {
            const int nn = q >> 4, ck = q & 15;
            int n = nodeBase + nn; if (n >= kN) n = kN - 1;
            const float4 xa = *reinterpret_cast<const float4*>(&x[(size_t)n * 128 + ck * 8]);
            const float4 xb = *reinterpret_cast<const float4*>(&x[(size_t)n * 128 + ck * 8 + 4]);
            float4 st;
            st.x = pack2h(xa.x, xa.y);
            st.y = pack2h(xa.z, xa.w);
            st.z = pack2h(xb.x, xb.y);
            st.w = pack2h(xb.z, xb.w);
            const int gran = nn * 16 + ((ck + nn) & 15);
            *reinterpret_cast<float4*>(&xsf[gran * 4]) = st;
        }
        __syncthreads();

        floatx4 acc0 = {0.f, 0.f, 0.f, 0.f};
        floatx4 acc1 = {0.f, 0.f, 0.f, 0.f};
        floatx4 acc2 = {0.f, 0.f, 0.f, 0.f};
        floatx4 acc3 = {0.f, 0.f, 0.f, 0.f};
        const int node = rt * 16 + lm;               // A row for this lane
        const int ch0  = ctB * 16 + lm;              // B col for this lane (tile 0)
#pragma unroll
        for (int kk = 0; kk < 4; ++kk) {
            const int ck = lk + 4 * kk;              // this lane's k-chunk (8 halves)
            const half8v af = *reinterpret_cast<const half8v*>(
                &xsf[(node * 16 + ((ck + node) & 15)) * 4]);
            const half8v b0 = *reinterpret_cast<const half8v*>(
                &whf[((ch0 +  0) * 16 + ((ck + ch0 +  0) & 15)) * 4]);
            const half8v b1 = *reinterpret_cast<const half8v*>(
                &whf[((ch0 + 16) * 16 + ((ck + ch0 + 16) & 15)) * 4]);
            const half8v b2 = *reinterpret_cast<const half8v*>(
                &whf[((ch0 + 32) * 16 + ((ck + ch0 + 32) & 15)) * 4]);
            const half8v b3 = *reinterpret_cast<const half8v*>(
                &whf[((ch0 + 48) * 16 + ((ck + ch0 + 48) & 15)) * 4]);
            acc0 = __builtin_amdgcn_mfma_f32_16x16x32_f16(af, b0, acc0, 0, 0, 0);
            acc1 = __builtin_amdgcn_mfma_f32_16x16x32_f16(af, b1, acc1, 0, 0, 0);
            acc2 = __builtin_amdgcn_mfma_f32_16x16x32_f16(af, b2, acc2, 0, 0, 0);
            acc3 = __builtin_amdgcn_mfma_f32_16x16x32_f16(af, b3, acc3, 0, 0, 0);
        }
        // D: col = lm, row = lk*4 + r
        const int nrow0 = nodeBase + rt * 16 + lk * 4;
#pragma unroll
        for (int r = 0; r < 4; ++r) {
            const int n = nrow0 + r;
            if (n < kN) {
                h1h[(size_t)n * 128 + ch0     ] = __float2half(acc0[r]);
                h1h[(size_t)n * 128 + ch0 + 16] = __float2half(acc1[r]);
                h1h[(size_t)n * 128 + ch0 + 32] = __float2half(acc2[r]);
                h1h[(size_t)n * 128 + ch0 + 48] = __float2half(acc3[r]);
            }
        }
        __syncthreads();
    }
}

// ---- attention logits from h1 (fp16): one wave per node, lane = 2 channels ----
__global__ __launch_bounds__(256)
void k_logits(const __half* __restrict__ h1h,
              const float* __restrict__ a_src1, const float* __restrict__ a_dst1,
              float* __restrict__ asrc, float* __restrict__ adst) {
    const int n = blockIdx.x * 4 + (threadIdx.x >> 6);
    if (n >= kN) return;
    const int j = threadIdx.x & 63;
    const float2 f = __half22float2(*(const __half2*)&h1h[(size_t)n * 128 + 2 * j]);
    float ps = f.x * a_src1[2 * j] + f.y * a_src1[2 * j + 1];
    float pd = f.x * a_dst1[2 * j] + f.y * a_dst1[2 * j + 1];
#pragma unroll
    for (int off = 8; off >= 1; off >>= 1) {
        ps += __shfl_xor(ps, off, 64);
        pd += __shfl_xor(pd, off, 64);
    }
    if ((j & 15) == 0) {
        asrc[n * 4 + (j >> 4)] = ps;
        adst[n * 4 + (j >> 4)] = pd;
    }
}

// ---- CSR build: hist also records each edge's rank within its dst bucket
//      (the atomic return we previously discarded) -> scatter needs no atomic.
__global__ void k_hist(const int* __restrict__ ei, int E, int* __restrict__ deg,
                       int* __restrict__ rank) {
    int i = blockIdx.x * blockDim.x + threadIdx.x;
    int total = E + kN;
    if (i >= total) return;
    int d = (i < E) ? ei[E + i] : (i - E);
    rank[i] = atomicAdd(&deg[d], 1);
}

__global__ void k_scan_a(const int* __restrict__ deg, int* __restrict__ loc, int* __restrict__ bsum) {
    __shared__ int tmp[kScanB];
    int t = threadIdx.x;
    int i = blockIdx.x * kScanB + t;
    int v = (i < kN) ? deg[i] : 0;
    tmp[t] = v;
    __syncthreads();
    for (int off = 1; off < kScanB; off <<= 1) {
        int add = (t >= off) ? tmp[t - off] : 0;
        __syncthreads();
        tmp[t] += add;
        __syncthreads();
    }
    if (i < kN) loc[i] = tmp[t] - v;     // exclusive within block
    if (t == kScanB - 1) bsum[blockIdx.x] = tmp[t];
}

__global__ void k_scan_b(int* __restrict__ bsum) {
    __shared__ int tmp[256];
    int t = threadIdx.x;
    int v = (t < kScanNB) ? bsum[t] : 0;
    tmp[t] = v;
    __syncthreads();
    for (int off = 1; off < 256; off <<= 1) {
        int add = (t >= off) ? tmp[t - off] : 0;
        __syncthreads();
        tmp[t] += add;
        __syncthreads();
    }
    if (t < kScanNB) bsum[t] = tmp[t] - v;   // exclusive
}

__global__ void k_scan_c(const int* __restrict__ loc, const int* __restrict__ bsum,
                         int* __restrict__ rowptr, int E2) {
    int i = blockIdx.x * kScanB + threadIdx.x;
    if (i < kN) rowptr[i] = loc[i] + bsum[blockIdx.x];
    if (i == 0) rowptr[kN] = E2;
}

// ---- scatter: pure permutation write (4B per edge), no atomic, no wgt
//      (R14: the 16B random wgt writes caused 80MB of HBM write amplification).
__global__ void k_scatter(const int* __restrict__ ei, int E,
                          const int* __restrict__ rowptr, const int* __restrict__ rank,
                          int* __restrict__ es) {
    int i = blockIdx.x * blockDim.x + threadIdx.x;
    int total = E + kN;
    if (i >= total) return;
    int s, d;
    if (i < E) { s = ei[i]; d = ei[E + i]; } else { s = d = i - E; }
    es[rowptr[d] + rank[i]] = s;
}

// ---- weights in CSR order: 16 lanes/node; lane writes wgt[p*4..] -> consecutive
//      lanes write consecutive 16B = coalesced streaming (no amplification).
__global__ __launch_bounds__(256)
void k_wgt(const int* __restrict__ rowptr, const int* __restrict__ es,
           const float* __restrict__ asrc, const float* __restrict__ adst,
           float* __restrict__ wgt) {
    const int n = blockIdx.x * 16 + (threadIdx.x >> 4);
    if (n >= kN) return;
    const int l = threadIdx.x & 15;
    const int beg = rowptr[n], end = rowptr[n + 1];
    const float ad0 = adst[n * 4 + 0], ad1 = adst[n * 4 + 1];
    const float ad2 = adst[n * 4 + 2], ad3 = adst[n * 4 + 3];
    for (int p = beg + l; p < end; p += 16) {
        const int s = es[p];
        float4 w4;
        w4.x = expf(lrelu(asrc[s * 4 + 0] + ad0));
        w4.y = expf(lrelu(asrc[s * 4 + 1] + ad1));
        w4.z = expf(lrelu(asrc[s * 4 + 2] + ad2));
        w4.w = expf(lrelu(asrc[s * 4 + 3] + ad3));
        *reinterpret_cast<float4*>(&wgt[(size_t)p * 4]) = w4;
    }
}

// ---- layer 1 aggregation: pure gather+FMA (weights preloaded), 4-unrolled ----
__global__ __launch_bounds__(256)
void k_agg1(const int* __restrict__ rowptr, const int* __restrict__ es,
            const float* __restrict__ wgt,
            const __half* __restrict__ h1h, const float* __restrict__ b1,
            const float* __restrict__ W2, float* __restrict__ h2) {
    const int n = blockIdx.x * 4 + (threadIdx.x >> 6);
    if (n >= kN) return;
    const int j  = threadIdx.x & 63;     // lane: channels 2j, 2j+1
    const int hh = j >> 4;               // head of both channels
    const int beg = rowptr[n], end = rowptr[n + 1];
    float ax0 = 0.f, ay0 = 0.f, dn0 = 0.f;
    float ax1 = 0.f, ay1 = 0.f, dn1 = 0.f;
    int p = beg;
    for (; p + 4 <= end; p += 4) {
        const int s0 = es[p],     s1 = es[p + 1];
        const int s2 = es[p + 2], s3 = es[p + 3];
        const float w0 = wgt[(p + 0) * 4 + hh];
        const float w1 = wgt[(p + 1) * 4 + hh];
        const float w2 = wgt[(p + 2) * 4 + hh];
        const float w3 = wgt[(p + 3) * 4 + hh];
        const float2 f0 = __half22float2(*(const __half2*)&h1h[s0 * 128 + 2 * j]);
        const float2 f1 = __half22float2(*(const __half2*)&h1h[s1 * 128 + 2 * j]);
        const float2 f2 = __half22float2(*(const __half2*)&h1h[s2 * 128 + 2 * j]);
        const float2 f3 = __half22float2(*(const __half2*)&h1h[s3 * 128 + 2 * j]);
        ax0 += w0 * f0.x; ay0 += w0 * f0.y; dn0 += w0;
        ax1 += w1 * f1.x; ay1 += w1 * f1.y; dn1 += w1;
        ax0 += w2 * f2.x; ay0 += w2 * f2.y; dn0 += w2;
        ax1 += w3 * f3.x; ay1 += w3 * f3.y; dn1 += w3;
    }
    for (; p < end; ++p) {
        const int s0 = es[p];
        const float w0 = wgt[p * 4 + hh];
        const float2 f0 = __half22float2(*(const __half2*)&h1h[s0 * 128 + 2 * j]);
        ax0 += w0 * f0.x; ay0 += w0 * f0.y; dn0 += w0;
    }
    const float den = dn0 + dn1;
    float vx = (ax0 + ax1) / den;
    float vy = (ay0 + ay1) / den;
    vx += __shfl_xor(vx, 32, 64); vy += __shfl_xor(vy, 32, 64);
    vx += __shfl_xor(vx, 16, 64); vy += __shfl_xor(vy, 16, 64);
    const int m = j & 15;
    float u0 = 0.25f * vx + b1[2 * m];
    float u1 = 0.25f * vy + b1[2 * m + 1];
    u0 = u0 > 0.f ? u0 : expf(u0) - 1.f;
    u1 = u1 > 0.f ? u1 : expf(u1) - 1.f;
    float tsum = u0 * W2[2 * m] + u1 * W2[2 * m + 1];
    tsum += __shfl_xor(tsum, 8, 64);
    tsum += __shfl_xor(tsum, 4, 64);
    tsum += __shfl_xor(tsum, 2, 64);
    tsum += __shfl_xor(tsum, 1, 64);
    if (j == 0) h2[n] = tsum;
}

// ---- layer 2: 16 lanes per node, gather h2 (L2-resident), fused bias -> out ----
__global__ __launch_bounds__(256)
void k_agg2(const int* __restrict__ rowptr, const int* __restrict__ es,
            const float* __restrict__ h2,
            const float* __restrict__ a_s2, const float* __restrict__ a_d2,
            const float* __restrict__ b2, float* __restrict__ out) {
    const int n = blockIdx.x * 16 + (threadIdx.x >> 4);
    if (n >= kN) return;
    const int l = threadIdx.x & 15;
    const float as = a_s2[0], ad = a_d2[0];
    const int beg = rowptr[n], end = rowptr[n + 1];
    const float hd = h2[n] * ad;
    float sw = 0.f, swh = 0.f;
    for (int p = beg + l; p < end; p += 16) {
        float hs = h2[es[p]];
        float w = expf(lrelu(hs * as + hd));
        sw += w;
        swh += w * hs;
    }
#pragma unroll
    for (int off = 8; off >= 1; off >>= 1) {
        sw  += __shfl_xor(sw, off, 64);
        swh += __shfl_xor(swh, off, 64);
    }
    if (l == 0) out[n] = swh / sw + b2[0];
}

extern "C" void kernel_launch(void* const* d_in, const int* in_sizes, int n_in,
                              void* d_out, int out_size, void* d_ws, size_t ws_size,
                              hipStream_t stream) {
    const float* x      = (const float*)d_in[0];
    const int*   ei     = (const int*)d_in[1];
    const float* W1     = (const float*)d_in[3];
    const float* a_src1 = (const float*)d_in[4];
    const float* a_dst1 = (const float*)d_in[5];
    const float* b1     = (const float*)d_in[6];
    const float* W2     = (const float*)d_in[7];
    const float* a_src2 = (const float*)d_in[8];
    const float* a_dst2 = (const float*)d_in[9];
    const float* b2     = (const float*)d_in[10];
    float* out = (float*)d_out;

    const int E  = in_sizes[1] / 2;      // 800000
    const int E2 = E + kN;               // 850000

    // workspace layout (float offsets)
    float*  ws    = (float*)d_ws;
    float*  asrc  = ws;                          //   200,000 f
    float*  adst  = ws + 200000;                 //   200,000 f
    float*  h2    = ws + 400000;                 //    50,000 f
    __half* h1h   = (__half*)(ws + 450000);      // 6,400,000 h = 3,200,000 f
    float*  wgt   = ws + 3650000;                // 3,400,000 f (per-edge weights x4)
    int*    ibase = (int*)(ws + 7050000);
    int*    es     = ibase;                      //   850,000 i
    int*    deg    = ibase + 850000;             //    50,000 i
    int*    rank   = ibase + 900000;             //   850,000 i
    int*    loc    = ibase + 1750000;            //    50,000 i
    int*    rowptr = ibase + 1800000;            //    50,001 i
    int*    bsum   = ibase + 1850016;            //       256 i

    k_init<<<(kN + 255) / 256, 256, 0, stream>>>(deg, kN);

    k_hist<<<(E2 + 255) / 256, 256, 0, stream>>>(ei, E, deg, rank);
    k_scan_a<<<kScanNB, kScanB, 0, stream>>>(deg, loc, bsum);
    k_scan_b<<<1, 256, 0, stream>>>(bsum);
    k_scan_c<<<kScanNB, kScanB, 0, stream>>>(loc, bsum, rowptr, E2);

    {
        const int nPass = (kN + 31) / 32;        // 1563
        const int grid  = 782;                   // ~2 passes/block
        k_gemm1<<<grid, 256, 0, stream>>>(x, W1, h1h, nPass, grid);
    }

    k_logits<<<(kN + 3) / 4, 256, 0, stream>>>(h1h, a_src1, a_dst1, asrc, adst);

    k_scatter<<<(E2 + 255) / 256, 256, 0, stream>>>(ei, E, rowptr, rank, es);

    k_wgt<<<(kN + 15) / 16, 256, 0, stream>>>(rowptr, es, asrc, adst, wgt);

    k_agg1<<<(kN + 3) / 4, 256, 0, stream>>>(rowptr, es, wgt, h1h, b1, W2, h2);

    k_agg2<<<(kN + 15) / 16, 256, 0, stream>>>(rowptr, es, h2, a_src2, a_dst2, b2, out);
}